// Round 16
// baseline (137.340 us; speedup 1.0000x reference)
//
#include <hip/hip_runtime.h>
#include <cstdint>

typedef _Float16 f16x8 __attribute__((ext_vector_type(8)));
typedef float f32x4 __attribute__((ext_vector_type(4)));
typedef _Float16 half2_t __attribute__((ext_vector_type(2)));

__device__ __forceinline__ unsigned pkh2(float a, float b) {
  return __builtin_bit_cast(unsigned, __builtin_amdgcn_cvt_pkrtz(a, b));
}
__device__ __forceinline__ float fast_tanh(float x) {
  float e = __builtin_amdgcn_exp2f(x * 2.885390081777927f);
  return 1.0f - 2.0f * __builtin_amdgcn_rcpf(e + 1.0f);
}

#if __has_builtin(__builtin_amdgcn_fdot2)
__device__ __forceinline__ float dot2h(unsigned a, unsigned b, float c) {
  return __builtin_amdgcn_fdot2(__builtin_bit_cast(half2_t, a),
                                __builtin_bit_cast(half2_t, b), c, false);
}
#else
__device__ __forceinline__ float dot2h(unsigned a, unsigned b, float c) {
  float d;
  asm("v_dot2_f32_f16 %0, %1, %2, %3" : "=v"(d) : "v"(a), "v"(b), "v"(c));
  return d;
}
#endif

// ---------------------------------------------------------------------------
// Stage 1 (r8-verified, byte-identical): per-(ks,bt,co) partial GEMM via
// fp16 MFMA. Epilogue -> co-major part[ks][bt][co][pos].
// ---------------------------------------------------------------------------
template <int ITERS>
__global__ __launch_bounds__(256, 2) void k_stage1(const float* __restrict__ x,
                                                   const float* __restrict__ w1,
                                                   const float* __restrict__ w3,
                                                   float* __restrict__ part,
                                                   unsigned* __restrict__ wtab) {
  constexpr int NS = 32 / ITERS;  // K-split count
  constexpr int KSB = (NS == 8) ? 3 : (NS == 4) ? 2 : (NS == 2) ? 1 : 0;
  __shared__ __align__(16) char lds_raw[64 * 65 * 4];      // 16640 B
  unsigned short* As = (unsigned short*)lds_raw;           // 64 rows * 40 hw
  unsigned short* Bs = (unsigned short*)(lds_raw + 5120);  // 64 rows * 40 hw
  float* Cs = (float*)lds_raw;                             // 64 x 65 fp32

  const int tid = threadIdx.x;
  if (blockIdx.x == 0) {  // legacy wtab pack (unused downstream; harmless)
    int l = tid << 2;
#pragma unroll
    for (int j = 0; j < 4; ++j) {
      int d = l + j;
      int slot = d & 3, chU = (d >> 2) & 1, kh = (d >> 3) & 3,
          kd = (d >> 5) & 3, cio = d >> 7;
      int co = (chU << 1) + (slot & 1);
      int kwb = (slot >> 1) << 1;
      int base = ((co << 3) + cio) * 64 + (kd << 4) + (kh << 2) + kwb;
      wtab[d] = pkh2(w3[base], w3[base + 1]);
    }
  }

  const int ks = blockIdx.x & (NS - 1);
  const int bt = (blockIdx.x >> KSB) & 15;
  const int co = blockIdx.x >> (KSB + 4);
  const int w = tid >> 6, lane = tid & 63, lm = lane & 15, q = lane >> 4;
  const int rrow = tid & 63, kgr = tid >> 6;

  f32x4 acc[4];
#pragma unroll
  for (int i = 0; i < 4; ++i) acc[i] = (f32x4){0.f, 0.f, 0.f, 0.f};

  const float* gA = x + (bt << 16) + ((size_t)(ks * ITERS * 32) << 6);
  const float* gB = w1 + (co << 6) + (size_t)(ks * ITERS * 32) * 512;

  float va[2][8], vb[2][8];
#define S1_LOAD(buf, it)                            \
  {                                                 \
    const int kb = (it) * 32 + (kgr << 3);          \
    _Pragma("unroll") for (int j = 0; j < 8; ++j) { \
      va[buf][j] = gA[((kb + j) << 6) | rrow];      \
      vb[buf][j] = gB[(kb + j) * 512 + rrow];       \
    }                                               \
  }
  S1_LOAD(0, 0);
#pragma unroll
  for (int it = 0; it < ITERS; ++it) {
    const int cur = it & 1;
    if (it + 1 < ITERS) S1_LOAD(cur ^ 1, it + 1);
    uint4 pa, pb;
    pa.x = pkh2(va[cur][0], va[cur][1]);
    pa.y = pkh2(va[cur][2], va[cur][3]);
    pa.z = pkh2(va[cur][4], va[cur][5]);
    pa.w = pkh2(va[cur][6], va[cur][7]);
    pb.x = pkh2(vb[cur][0], vb[cur][1]);
    pb.y = pkh2(vb[cur][2], vb[cur][3]);
    pb.z = pkh2(vb[cur][4], vb[cur][5]);
    pb.w = pkh2(vb[cur][6], vb[cur][7]);
    *(uint4*)&As[rrow * 40 + (kgr << 3)] = pa;
    *(uint4*)&Bs[rrow * 40 + (kgr << 3)] = pb;
    __syncthreads();
    f16x8 a = *(const f16x8*)&As[((w << 4) + lm) * 40 + (q << 3)];
#pragma unroll
    for (int nf = 0; nf < 4; ++nf) {
      f16x8 b = *(const f16x8*)&Bs[((nf << 4) + lm) * 40 + (q << 3)];
      acc[nf] = __builtin_amdgcn_mfma_f32_16x16x32_f16(a, b, acc[nf], 0, 0, 0);
    }
    __syncthreads();
  }
#undef S1_LOAD
#pragma unroll
  for (int nf = 0; nf < 4; ++nf)
#pragma unroll
    for (int r = 0; r < 4; ++r) {
      int m = (w << 4) + (q << 2) + r;
      int n = (nf << 4) + lm;
      Cs[m * 65 + n] = acc[nf][r];
    }
  __syncthreads();
  float* dst = part + (((size_t)(((ks << 4) + bt) << 3) + co) << 12);
#pragma unroll
  for (int j = 0; j < 4; ++j) {
    int pos = (tid << 2) + (j << 10);
    int z = pos >> 8, y = (pos >> 4) & 15, xx = pos & 15;
    int m = ((z >> 2) << 4) + ((y >> 2) << 2) + (xx >> 2);
    int n = ((z & 3) << 4) + ((y & 3) << 2);
    float4 v;
    v.x = Cs[m * 65 + n + 0];
    v.y = Cs[m * 65 + n + 1];
    v.z = Cs[m * 65 + n + 2];
    v.w = Cs[m * 65 + n + 3];
    *(float4*)&dst[pos] = v;
  }
}

// ---------------------------------------------------------------------------
// Fused stage 2+3, r15 = r14 MFMA-conv kernel + RUN-GROUPED fill.
// Key fact: window cells on one x-run of a fixed kx class (wx = first+4i,
// first=(ax+1)&3, kx=ax since Qx0 % 4 == 3) share (kz,ky,kx) -> the SAME
// 8 w2 fragments. Fill = 1296 runs (18 wz x 18 wy x 4 ax), 4-5 cells each:
// per run hoist 8 w2 b128 reads into regs (wf[8]), then per cell only
// 1 h-read + 32 dot2 + 8 tanh. Fill LDS reads/thread: 54 -> ~13.
// Runs mapped 81/wave (contiguous -> ax nearly wave-uniform; r12 lesson).
// __launch_bounds__(1024,4) = exactly the LDS-forced occupancy so the
// wf[8] hoist isn't rematerialized (r9 lesson; VGPR_Count must rise).
// Staging, w2p/w3p layouts, MFMA conv, epilogue identical to r14-verified.
// ---------------------------------------------------------------------------
template <int NSPLIT>
__global__ __launch_bounds__(1024, 4) void k_stage23(
    const float* __restrict__ part, const float* __restrict__ w2,
    const float* __restrict__ b2, const float* __restrict__ b3,
    const float* __restrict__ b1, const float* __restrict__ w3,
    float* __restrict__ out) {
  __shared__ __align__(16) unsigned win[18 * 18 * 18 * 4];  // 93312 B
  __shared__ __align__(16) unsigned h1p[216 * 4];           // 3456 B
  __shared__ __align__(16) unsigned w2p[8 * 320];           // 10240 B
  __shared__ __align__(16) unsigned w3p[16 * 64 * 4];       // 16384 B

  const int tid = threadIdx.x;
  const int bid = blockIdx.x;
  const int tile = bid & 63;  // bid%8 = (ty&1)<<2 | tx -> XCD colocation
  const int bt = bid >> 6;
  const int tz = tile >> 4, ty = (tile >> 2) & 3, tx = tile & 3;
  const int Z0 = tz << 3, Y0 = ty << 3, X0 = tx << 3;
  const int Qz0 = (Z0 << 1) - 1, Qy0 = (Y0 << 1) - 1, Qx0 = (X0 << 1) - 1;
  const int Uz0 = Qz0 >> 2, Uy0 = Qy0 >> 2, Ux0 = Qx0 >> 2;

  // ---- staging: h1 = tanh(sum_s part + b1) -> h1p cells [uz][uy][ux][ci8]
#pragma unroll
  for (int k = 0; k < 2; ++k) {
    int l = tid + (k << 10);
    bool vld = l < 1728;
    int ll = vld ? l : 0;
    int ci = ll / 216;
    int sp = ll - ci * 216;
    int uz = sp / 36;
    int t1 = sp - uz * 36;
    int uy = t1 / 6;
    int ux = t1 - uy * 6;
    int gz = Uz0 + uz, gy = Uy0 + uy, gx = Ux0 + ux;
    bool inb = vld && (unsigned)gz < 16u && (unsigned)gy < 16u &&
               (unsigned)gx < 16u;
    float v = 0.f;
    if (inb) {
      const float* p =
          part + (((size_t)(bt << 3) + ci) << 12) + (gz << 8) + (gy << 4) + gx;
      float s = b1[ci];
#pragma unroll
      for (int sg = 0; sg < NSPLIT; ++sg) s += p[(size_t)sg << 19];
      v = fast_tanh(s);
    }
    if (vld)
      ((_Float16*)h1p)[(((uz * 6 + uy) * 6 + ux) << 3) + ci] = (_Float16)v;
  }

  // ---- w2 pack: dword = [cio][kzy stride20][kx*4+j] (per (cio,kpos) b128)
  for (int l = tid; l < 2048; l += 1024) {
    int j = l & 3, kx = (l >> 2) & 3, kzy = (l >> 4) & 15, cio = l >> 8;
    int kpos = (kzy << 2) + kx;
    float w0 = w2[(((j << 1) << 3) + cio) * 64 + kpos];
    float w1v = w2[((((j << 1) + 1) << 3) + cio) * 64 + kpos];
    w2p[cio * 320 + kzy * 20 + (kx << 2) + j] = pkh2(w0, w1v);
  }

  // ---- w3 MFMA B-fragment pack: slot = [kdkh 16][lane 64] of 8 fp16
  {
    int l = tid;
    int lane = l & 63;
    int kdkh = l >> 6;
    int co = lane & 15, kw = lane >> 4;
    int kd = kdkh >> 2, kh = kdkh & 3;
    uint4 v;
    v.x = v.y = v.z = v.w = 0u;
    if (co < 4) {
      int base = (co << 3) * 64 + (kd << 4) + (kh << 2) + kw;  // cio stride 64
      v.x = pkh2(w3[base], w3[base + 64]);
      v.y = pkh2(w3[base + 128], w3[base + 192]);
      v.z = pkh2(w3[base + 256], w3[base + 320]);
      v.w = pkh2(w3[base + 384], w3[base + 448]);
    }
    *(uint4*)&w3p[l << 2] = v;
  }

  // ---- run precompute: 1296 runs = [ax 4][wz 18][wy 18]; wave w owns runs
  // [w*81, (w+1)*81): lane l does run w*81+l and +64 (l<17).
  const int wavef = tid >> 6, lanef = tid & 63;
  const int runb = wavef * 81 + lanef;
  int p_w2[2], p_h[2], p_w[2], p_cnt[2], p_qx0[2];
  bool p_rowok[2];
#pragma unroll
  for (int s = 0; s < 2; ++s) {
    int run = runb + (s << 6);
    bool hv = (s == 0) ? (lanef < 81) : (lanef < 17);
    int rr = hv ? run : 0;
    int ax = rr / 324;
    int rem = rr - ax * 324;
    int wz = rem / 18;
    int wy = rem - wz * 18;
    int qz = Qz0 + wz, qy = Qy0 + wy;
    p_rowok[s] = hv && (unsigned)qz < 64u && (unsigned)qy < 64u;
    int kzy = ((qz & 3) << 2) | (qy & 3);
    int first = (ax + 1) & 3;
    p_cnt[s] = hv ? ((21 - first) >> 2) : 0;  // 5,4,4,5 for ax 0..3
    p_w2[s] = kzy * 20 + (ax << 2);           // + cio*320 ; kx == ax
    int qx0 = Qx0 + first;
    p_qx0[s] = qx0;
    int ux0 = (qx0 >> 2) - Ux0;
    p_h[s] = ((((qz >> 2) - Uz0) * 6 + ((qy >> 2) - Uy0)) * 6 + ux0) << 2;
    p_w[s] = ((wz * 18 + wy) * 18 + first) << 2;  // + i*16 dwords
  }
  float b2v[8];
#pragma unroll
  for (int c = 0; c < 8; ++c) b2v[c] = b2[c];

  __syncthreads();  // staging + packs visible

  // ---- fill: run-grouped; per run hoist 8 w2 frags, 4-5 cells each
#pragma unroll
  for (int s = 0; s < 2; ++s) {
    if (p_cnt[s] == 0) continue;
    uint4 wf[8];
    if (p_rowok[s]) {
#pragma unroll
      for (int c = 0; c < 8; ++c)
        wf[c] = *(const uint4*)&w2p[c * 320 + p_w2[s]];
    }
#pragma unroll
    for (int i = 0; i < 5; ++i) {
      if (i < p_cnt[s]) {
        int qx = p_qx0[s] + (i << 2);
        bool ok = p_rowok[s] && (unsigned)qx < 64u;
        uint4 sv;
        sv.x = sv.y = sv.z = sv.w = 0u;
        if (ok) {
          uint4 h = *(const uint4*)&h1p[p_h[s] + (i << 2)];
          float vals[8];
#pragma unroll
          for (int c = 0; c < 8; ++c)
            vals[c] = fast_tanh(
                dot2h(h.w, wf[c].w,
                      dot2h(h.z, wf[c].z,
                            dot2h(h.y, wf[c].y,
                                  dot2h(h.x, wf[c].x, b2v[c])))));
          sv.x = pkh2(vals[0], vals[1]);
          sv.y = pkh2(vals[2], vals[3]);
          sv.z = pkh2(vals[4], vals[5]);
          sv.w = pkh2(vals[6], vals[7]);
        }
        *(uint4*)&win[p_w[s] + (i << 4)] = sv;
      }
    }
  }
  __syncthreads();  // window complete

  // ---- conv: MFMA. 16 waves; wave handles 2 M-tiles (id = i*16 + wave)
  const int wave = tid >> 6, lane = tid & 63;
  const int n = lane & 15, q = lane >> 4;          // D col (co), kw/row-blk
  const int yy = (lane & 15) >> 3, xl = lane & 7;  // A row -> pos (yy,x)
  f32x4 acc[2];
  int celloff[2];
#pragma unroll
  for (int i = 0; i < 2; ++i) {
    acc[i] = (f32x4){0.f, 0.f, 0.f, 0.f};
    int id = (i << 4) + wave;
    int zq = id >> 2, yp = id & 3;
    celloff[i] =
        ((((zq << 1) * 18 + (yp << 2) + (yy << 1)) * 18 + (xl << 1) + q) << 2);
  }
#pragma unroll
  for (int kd = 0; kd < 4; ++kd) {
#pragma unroll
    for (int kh = 0; kh < 4; ++kh) {
      f16x8 B = *(const f16x8*)&w3p[((((kd << 2) + kh) << 6) | lane) << 2];
      const int koff = (kd * 324 + kh * 18) << 2;
#pragma unroll
      for (int i = 0; i < 2; ++i) {
        f16x8 A = *(const f16x8*)&win[celloff[i] + koff];
        acc[i] = __builtin_amdgcn_mfma_f32_16x16x32_f16(A, B, acc[i], 0, 0, 0);
      }
    }
  }

  // ---- epilogue: lanes n<4 hold co=n; rows m = q*4+r -> pos (yy2, x2)
  if (n < 4) {
    const float bias = b3[n];
    const int b = bt >> 3, t8 = bt & 7;
#pragma unroll
    for (int i = 0; i < 2; ++i) {
      int id = (i << 4) + wave;
      int zq = id >> 2, yp = id & 3;
      int z = Z0 + zq;
#pragma unroll
      for (int r = 0; r < 4; ++r) {
        int m = (q << 2) + r;
        int yy2 = m >> 3, x2 = m & 7;
        int y = Y0 + (yp << 1) + yy2;
        int xx = X0 + x2;
        out[(((((b << 2) + n) * 32 + z) * 32 + y) * 32 + xx) << 3 | t8] =
            acc[i][r] + bias;
      }
    }
  }
}

extern "C" void kernel_launch(void* const* d_in, const int* in_sizes, int n_in,
                              void* d_out, int out_size, void* d_ws,
                              size_t ws_size, hipStream_t stream) {
  (void)in_sizes; (void)n_in; (void)out_size;
  const float* x = (const float*)d_in[0];
  const float* w1 = (const float*)d_in[1];
  const float* b1 = (const float*)d_in[2];
  const float* w2 = (const float*)d_in[3];
  const float* b2 = (const float*)d_in[4];
  const float* w3 = (const float*)d_in[5];
  const float* b3 = (const float*)d_in[6];
  float* out = (float*)d_out;
  float* part = (float*)d_ws;

  const size_t plane = (size_t)16 * 8 * 4096;  // floats per split (2 MB)
  int nsplit = 1;
  if (ws_size >= 4 * plane * 4 + 4096)
    nsplit = 4;
  else if (ws_size >= 2 * plane * 4 + 4096)
    nsplit = 2;
  unsigned* wtab = (unsigned*)(part + (size_t)nsplit * plane);

  switch (nsplit) {
    case 4:
      k_stage1<8><<<dim3(512), dim3(256), 0, stream>>>(x, w1, w3, part, wtab);
      k_stage23<4><<<dim3(1024), dim3(1024), 0, stream>>>(part, w2, b2, b3, b1,
                                                          w3, out);
      break;
    case 2:
      k_stage1<16><<<dim3(256), dim3(256), 0, stream>>>(x, w1, w3, part, wtab);
      k_stage23<2><<<dim3(1024), dim3(1024), 0, stream>>>(part, w2, b2, b3, b1,
                                                          w3, out);
      break;
    default:
      k_stage1<32><<<dim3(128), dim3(256), 0, stream>>>(x, w1, w3, part, wtab);
      k_stage23<1><<<dim3(1024), dim3(1024), 0, stream>>>(part, w2, b2, b3, b1,
                                                          w3, out);
      break;
  }
}

// Round 17
// 127.826 us; speedup vs baseline: 1.0744x; 1.0744x over previous
//
#include <hip/hip_runtime.h>
#include <cstdint>

typedef _Float16 f16x8 __attribute__((ext_vector_type(8)));
typedef float f32x4 __attribute__((ext_vector_type(4)));
typedef _Float16 half2_t __attribute__((ext_vector_type(2)));

__device__ __forceinline__ unsigned pkh2(float a, float b) {
  return __builtin_bit_cast(unsigned, __builtin_amdgcn_cvt_pkrtz(a, b));
}
__device__ __forceinline__ float fast_tanh(float x) {
  float e = __builtin_amdgcn_exp2f(x * 2.885390081777927f);
  return 1.0f - 2.0f * __builtin_amdgcn_rcpf(e + 1.0f);
}

// Packed fp16 pair dot with f32 accumulate: d = a.lo*b.lo + a.hi*b.hi + c
#if __has_builtin(__builtin_amdgcn_fdot2)
__device__ __forceinline__ float dot2h(unsigned a, unsigned b, float c) {
  return __builtin_amdgcn_fdot2(__builtin_bit_cast(half2_t, a),
                                __builtin_bit_cast(half2_t, b), c, false);
}
#else
__device__ __forceinline__ float dot2h(unsigned a, unsigned b, float c) {
  float d;
  asm("v_dot2_f32_f16 %0, %1, %2, %3" : "=v"(d) : "v"(a), "v"(b), "v"(c));
  return d;
}
#endif

// ---------------------------------------------------------------------------
// Stage 1 (r8-verified): per-(ks,bt,co) partial GEMM via fp16 MFMA,
// __launch_bounds__(256,2) (128-VGPR budget, no spill).
// Epilogue -> co-major part[ks][bt][co][pos]. Block 0 packs w3 into wtab.
// ---------------------------------------------------------------------------
template <int ITERS>
__global__ __launch_bounds__(256, 2) void k_stage1(const float* __restrict__ x,
                                                   const float* __restrict__ w1,
                                                   const float* __restrict__ w3,
                                                   float* __restrict__ part,
                                                   unsigned* __restrict__ wtab) {
  constexpr int NS = 32 / ITERS;  // K-split count
  constexpr int KSB = (NS == 8) ? 3 : (NS == 4) ? 2 : (NS == 2) ? 1 : 0;
  __shared__ __align__(16) char lds_raw[64 * 65 * 4];      // 16640 B
  unsigned short* As = (unsigned short*)lds_raw;           // 64 rows * 40 hw
  unsigned short* Bs = (unsigned short*)(lds_raw + 5120);  // 64 rows * 40 hw
  float* Cs = (float*)lds_raw;                             // 64 x 65 fp32

  const int tid = threadIdx.x;
  // w3 pack: dword d = [cio][kd][kh][chU][slot: A0 A1 B0 B1], fp16 pairs
  if (blockIdx.x == 0) {
    int l = tid << 2;
#pragma unroll
    for (int j = 0; j < 4; ++j) {
      int d = l + j;
      int slot = d & 3, chU = (d >> 2) & 1, kh = (d >> 3) & 3,
          kd = (d >> 5) & 3, cio = d >> 7;
      int co = (chU << 1) + (slot & 1);
      int kwb = (slot >> 1) << 1;
      int base = ((co << 3) + cio) * 64 + (kd << 4) + (kh << 2) + kwb;
      wtab[d] = pkh2(w3[base], w3[base + 1]);
    }
  }

  const int ks = blockIdx.x & (NS - 1);
  const int bt = (blockIdx.x >> KSB) & 15;
  const int co = blockIdx.x >> (KSB + 4);
  const int w = tid >> 6, lane = tid & 63, lm = lane & 15, q = lane >> 4;
  const int rrow = tid & 63, kgr = tid >> 6;

  f32x4 acc[4];
#pragma unroll
  for (int i = 0; i < 4; ++i) acc[i] = (f32x4){0.f, 0.f, 0.f, 0.f};

  const float* gA = x + (bt << 16) + ((size_t)(ks * ITERS * 32) << 6);
  const float* gB = w1 + (co << 6) + (size_t)(ks * ITERS * 32) * 512;

  float va[2][8], vb[2][8];
#define S1_LOAD(buf, it)                            \
  {                                                 \
    const int kb = (it) * 32 + (kgr << 3);          \
    _Pragma("unroll") for (int j = 0; j < 8; ++j) { \
      va[buf][j] = gA[((kb + j) << 6) | rrow];      \
      vb[buf][j] = gB[(kb + j) * 512 + rrow];       \
    }                                               \
  }
  S1_LOAD(0, 0);
#pragma unroll
  for (int it = 0; it < ITERS; ++it) {
    const int cur = it & 1;
    if (it + 1 < ITERS) S1_LOAD(cur ^ 1, it + 1);
    uint4 pa, pb;
    pa.x = pkh2(va[cur][0], va[cur][1]);
    pa.y = pkh2(va[cur][2], va[cur][3]);
    pa.z = pkh2(va[cur][4], va[cur][5]);
    pa.w = pkh2(va[cur][6], va[cur][7]);
    pb.x = pkh2(vb[cur][0], vb[cur][1]);
    pb.y = pkh2(vb[cur][2], vb[cur][3]);
    pb.z = pkh2(vb[cur][4], vb[cur][5]);
    pb.w = pkh2(vb[cur][6], vb[cur][7]);
    *(uint4*)&As[rrow * 40 + (kgr << 3)] = pa;
    *(uint4*)&Bs[rrow * 40 + (kgr << 3)] = pb;
    __syncthreads();
    f16x8 a = *(const f16x8*)&As[((w << 4) + lm) * 40 + (q << 3)];
#pragma unroll
    for (int nf = 0; nf < 4; ++nf) {
      f16x8 b = *(const f16x8*)&Bs[((nf << 4) + lm) * 40 + (q << 3)];
      acc[nf] = __builtin_amdgcn_mfma_f32_16x16x32_f16(a, b, acc[nf], 0, 0, 0);
    }
    __syncthreads();
  }
#undef S1_LOAD
  // ---- epilogue: C -> LDS transpose -> contiguous co-major store
#pragma unroll
  for (int nf = 0; nf < 4; ++nf)
#pragma unroll
    for (int r = 0; r < 4; ++r) {
      int m = (w << 4) + (q << 2) + r;
      int n = (nf << 4) + lm;
      Cs[m * 65 + n] = acc[nf][r];
    }
  __syncthreads();
  float* dst = part + (((size_t)(((ks << 4) + bt) << 3) + co) << 12);
#pragma unroll
  for (int j = 0; j < 4; ++j) {
    int pos = (tid << 2) + (j << 10);  // lanes consecutive in 16B chunks
    int z = pos >> 8, y = (pos >> 4) & 15, xx = pos & 15;
    int m = ((z >> 2) << 4) + ((y >> 2) << 2) + (xx >> 2);
    int n = ((z & 3) << 4) + ((y & 3) << 2);  // + (xx&3) = 0..3 consecutive
    float4 v;
    v.x = Cs[m * 65 + n + 0];
    v.y = Cs[m * 65 + n + 1];
    v.z = Cs[m * 65 + n + 2];
    v.w = Cs[m * 65 + n + 3];
    *(float4*)&dst[pos] = v;
  }
}

// ---------------------------------------------------------------------------
// Fused stage 2+3 (r12-verified, session best: 59.5us): 512 thr, 512 blocks,
// z8 y16 x8 tile, window 18x34, double-buffered, ONE barrier per cio.
// Fill unit mapping u -> (half = u>=612, p = u-612*half, wz = p/34,
// wy = p%34): half is wave-uniform, so each fill wave executes ONE of the
// two fill bodies (the old u&1 mapping ran both with half-masked lanes =
// 2x fill issue cost; fixing this was -14.5us, the session's key win).
// XCD map bid%8 = (ty<<2)|tx: all bt of a tile colocate -> out lines
// (t innermost) assembled in one L2 (WRITE 8MB). fp16 fdot2 throughout,
// T14 async staging, w3 via wave-uniform scalar loads from wtab.
// ---------------------------------------------------------------------------
template <int NSPLIT>
__global__ __launch_bounds__(512) void k_stage23(
    const float* __restrict__ part, const float* __restrict__ w2,
    const float* __restrict__ b2, const float* __restrict__ b3,
    const float* __restrict__ b1, const unsigned* __restrict__ wtab,
    float* __restrict__ out) {
  __shared__ __align__(16) unsigned win_d[2][18 * 34 * 12];  // 58752 B
  __shared__ __align__(16) unsigned h1p[6 * 280];            // fp16 pairs
  __shared__ __align__(16) unsigned w2p[8 * 320];            // fp16 pairs

  const int tid = threadIdx.x;
  const int bid = blockIdx.x;
  const int tile = bid & 31;  // bid%8 = (ty<<2)|tx -> XCD column mapping
  const int bt = bid >> 5;
  const int tz = tile >> 3, ty = (tile >> 2) & 1, tx = tile & 3;
  const int Z0 = tz << 3, Y0 = ty << 4, X0 = tx << 3;
  const int Qz0 = (Z0 << 1) - 1, Qy0 = (Y0 << 1) - 1, Qx0 = (X0 << 1) - 1;
  const int Uz0 = Qz0 >> 2, Uy0 = Qy0 >> 2, Ux0 = Qx0 >> 2;

  // ---- phase A: issue part loads early (latency hides under w2/prepass)
  float sv[6][NSPLIT];
  float b1v[6];
  int dsto[6];
  bool inb[6];
#pragma unroll
  for (int k = 0; k < 6; ++k) {
    int l = tid + (k << 9);
    bool vld = l < 2880;
    int ll = vld ? l : 0;
    int ci = ll / 360;
    int sp = ll - ci * 360;
    int ux = sp % 6;
    int t1 = sp / 6;
    int uy = t1 % 10;
    int uz = t1 / 10;  // 0..5
    int gz = Uz0 + uz, gy = Uy0 + uy, gx = Ux0 + ux;
    inb[k] = vld && (unsigned)gz < 16u && (unsigned)gy < 16u &&
             (unsigned)gx < 16u;
    dsto[k] = vld ? (uz * 560 + uy * 56 + (ux << 3) + ci) : -1;
    b1v[k] = 0.f;
    if (inb[k]) {
      b1v[k] = b1[ci];
      const float* p =
          part + (((size_t)(bt << 3) + ci) << 12) + (gz << 8) + (gy << 4) + gx;
#pragma unroll
      for (int sg = 0; sg < NSPLIT; ++sg) sv[k][sg] = p[(size_t)sg << 19];
    }
  }

  // ---- w2 pack: dword = [cio][kz*4+ky (stride 20dw)][kx*4 + jpair]
  for (int l = tid; l < 2048; l += 512) {
    int j = l & 3, kx = (l >> 2) & 3, kzy = (l >> 4) & 15, cio = l >> 8;
    int kpos = (kzy << 2) + kx;
    float w0 = w2[(((j << 1) << 3) + cio) * 64 + kpos];
    float w1v = w2[((((j << 1) + 1) << 3) + cio) * 64 + kpos];
    w2p[cio * 320 + kzy * 20 + (kx << 2) + j] = pkh2(w0, w1v);
  }
  // ---- prepass: zero OOB rows of BOTH window buffers (skipped in-loop)
  for (int u = tid; u < 1224; u += 512) {
    int wz = u / 68;
    int rem = u - wz * 68;
    int wy = rem >> 1;
    int half = rem & 1;
    int qz = Qz0 + wz, qy = Qy0 + wy;
    if ((unsigned)qz < 64u && (unsigned)qy < 64u) continue;
    uint4 zz;
    zz.x = zz.y = zz.z = zz.w = 0u;
#pragma unroll
    for (int bsel = 0; bsel < 2; ++bsel) {
      unsigned* wrow = win_d[bsel] + (wz * 34 + wy) * 12;
      if (half == 0) {
        *(uint4*)wrow = zz;
      } else {
        *(uint4*)(wrow + 4) = zz;
        wrow[8] = 0u;
      }
    }
  }

  // ---- phase B: reduce splits + tanh -> h1p (fp16, ci innermost)
#pragma unroll
  for (int k = 0; k < 6; ++k) {
    if (dsto[k] < 0) continue;
    float v = 0.f;
    if (inb[k]) {
      float s = b1v[k];
#pragma unroll
      for (int sg = 0; sg < NSPLIT; ++sg) s += sv[k][sg];
      v = fast_tanh(s);
    }
    ((_Float16*)h1p)[dsto[k]] = (_Float16)v;
  }

  // ---- fill-unit precompute (invariant across cio)
  // r12 mapping: half = u>=612 (wave-uniform), p = u-612*half,
  // wz = p/34, wy = p%34. 612 = 18*34 cells per half.
  int fu_row[3], fu_h1[3], fu_w2[3], fu_half[3];
  bool fu_act[3];
#pragma unroll
  for (int k = 0; k < 3; ++k) {
    int u = tid + (k << 9);
    bool act = u < 1224;
    int uu = act ? u : 0;
    int half = (uu >= 612) ? 1 : 0;
    int p = uu - half * 612;
    int wz = p / 34;
    int wy = p - wz * 34;
    int qz = Qz0 + wz, qy = Qy0 + wy;
    fu_act[k] = act && (unsigned)qz < 64u && (unsigned)qy < 64u;
    fu_row[k] = (wz * 34 + wy) * 12;
    int kz = qz & 3, ky = qy & 3;
    fu_w2[k] = ((kz << 2) + ky) * 20;
    int uzp = (qz >> 2) - Uz0, uyp = (qy >> 2) - Uy0;
    fu_h1[k] = uzp * 280 + uyp * 28;
    fu_half[k] = half;
  }
  const bool gLo = (Qx0 >= 0), gHi = (Qx0 + 17 < 64);

  __syncthreads();  // staging + prepass + h1p visible

  float acc[2][4];  // [cc][i]
#pragma unroll
  for (int a = 0; a < 2; ++a)
#pragma unroll
    for (int i = 0; i < 4; ++i) acc[a][i] = 0.f;

  const int xh = tid & 1, yq = (tid >> 1) & 15, zq = (tid >> 5) & 7;
  const int chS = __builtin_amdgcn_readfirstlane(tid >> 8);  // wave-uniform

  for (int cio = 0; cio < 8; ++cio) {
    unsigned* wbuf = win_d[cio & 1];
    const float b2c = b2[cio];
    // ---- fill window: up to 3 precomputed units per thread
#pragma unroll
    for (int k = 0; k < 3; ++k) {
      if (!fu_act[k]) continue;
      unsigned* wrow = wbuf + fu_row[k];
      const unsigned* w2b = w2p + cio * 320 + fu_w2[k];
      uint4 wv[4];
#pragma unroll
      for (int kx = 0; kx < 4; ++kx) wv[kx] = *(const uint4*)(w2b + (kx << 2));
      const unsigned* h1b = h1p + fu_h1[k];
#define DOT8(hc, kx)                                            \
  dot2h((hc).w, wv[kx].w,                                       \
        dot2h((hc).z, wv[kx].z,                                 \
              dot2h((hc).y, wv[kx].y, dot2h((hc).x, wv[kx].x, b2c))))
      if (fu_half[k] == 0) {  // wx 0..7
        uint4 h0 = *(const uint4*)(h1b);
        uint4 h1c = *(const uint4*)(h1b + 4);
        uint4 h2c = *(const uint4*)(h1b + 8);
        float vals[8];
        vals[0] = gLo ? fast_tanh(DOT8(h0, 3)) : 0.f;
#pragma unroll
        for (int kx = 0; kx < 4; ++kx) vals[1 + kx] = fast_tanh(DOT8(h1c, kx));
#pragma unroll
        for (int kx = 0; kx < 3; ++kx) vals[5 + kx] = fast_tanh(DOT8(h2c, kx));
        uint4 s0;
        s0.x = pkh2(vals[0], vals[1]);
        s0.y = pkh2(vals[2], vals[3]);
        s0.z = pkh2(vals[4], vals[5]);
        s0.w = pkh2(vals[6], vals[7]);
        *(uint4*)wrow = s0;
      } else {  // wx 8..17
        uint4 h2c = *(const uint4*)(h1b + 8);
        uint4 h3 = *(const uint4*)(h1b + 12);
        uint4 h4 = *(const uint4*)(h1b + 16);
        uint4 h5 = *(const uint4*)(h1b + 20);
        float vals[10];
        vals[0] = fast_tanh(DOT8(h2c, 3));
#pragma unroll
        for (int kx = 0; kx < 4; ++kx) vals[1 + kx] = fast_tanh(DOT8(h3, kx));
#pragma unroll
        for (int kx = 0; kx < 4; ++kx) vals[5 + kx] = fast_tanh(DOT8(h4, kx));
        vals[9] = gHi ? fast_tanh(DOT8(h5, 0)) : 0.f;
        uint4 s1;
        s1.x = pkh2(vals[0], vals[1]);
        s1.y = pkh2(vals[2], vals[3]);
        s1.z = pkh2(vals[4], vals[5]);
        s1.w = pkh2(vals[6], vals[7]);
        *(uint4*)(wrow + 4) = s1;
        wrow[8] = pkh2(vals[8], vals[9]);
      }
#undef DOT8
    }
    __syncthreads();  // fill(cio) complete; conv(cio) overlaps fill(cio+1)
    // ---- conv3 accumulation: w3 scalar loads, win LDS rows
#pragma unroll
    for (int kd = 0; kd < 4; ++kd) {
      int wz = (zq << 1) + kd;
#pragma unroll
      for (int kh = 0; kh < 4; ++kh) {
        int wy = (yq << 1) + kh;
        const unsigned* rowp = wbuf + (wz * 34 + wy) * 12 + (xh << 2);
        uint4 rv = *(const uint4*)rowp;
        unsigned r4 = rowp[4];
        unsigned r[5] = {rv.x, rv.y, rv.z, rv.w, r4};
        const uint4 wv =
            *(const uint4*)&wtab[((((cio << 4) + (kd << 2) + kh) << 1) + chS)
                                 << 2];
        unsigned wA[2] = {wv.x, wv.y};
        unsigned wB[2] = {wv.z, wv.w};
#pragma unroll
        for (int cc = 0; cc < 2; ++cc) {
#pragma unroll
          for (int i = 0; i < 4; ++i) {
            float a0 = dot2h(r[i], wA[cc], acc[cc][i]);
            acc[cc][i] = dot2h(r[i + 1], wB[cc], a0);
          }
        }
      }
    }
  }
  // ---- epilogue: + b3, store to (B, C, 32,32,32, T) with t innermost
  const int ch = tid >> 8;
  const int b = bt >> 3, t8 = bt & 7;
  const int z = Z0 + zq;
  const int y = Y0 + yq;
#pragma unroll
  for (int cc = 0; cc < 2; ++cc) {
    int c4 = (ch << 1) + cc;
    float bias = b3[c4];
#pragma unroll
    for (int i = 0; i < 4; ++i) {
      int xx = X0 + (xh << 2) + i;
      out[(((((b << 2) + c4) * 32 + z) * 32 + y) * 32 + xx) << 3 | t8] =
          acc[cc][i] + bias;
    }
  }
}

extern "C" void kernel_launch(void* const* d_in, const int* in_sizes, int n_in,
                              void* d_out, int out_size, void* d_ws,
                              size_t ws_size, hipStream_t stream) {
  (void)in_sizes; (void)n_in; (void)out_size;
  const float* x = (const float*)d_in[0];
  const float* w1 = (const float*)d_in[1];
  const float* b1 = (const float*)d_in[2];
  const float* w2 = (const float*)d_in[3];
  const float* b2 = (const float*)d_in[4];
  const float* w3 = (const float*)d_in[5];
  const float* b3 = (const float*)d_in[6];
  float* out = (float*)d_out;
  float* part = (float*)d_ws;

  const size_t plane = (size_t)16 * 8 * 4096;  // floats per split (2 MB)
  int nsplit = 1;
  if (ws_size >= 4 * plane * 4 + 4096)
    nsplit = 4;
  else if (ws_size >= 2 * plane * 4 + 4096)
    nsplit = 2;
  unsigned* wtab = (unsigned*)(part + (size_t)nsplit * plane);

  switch (nsplit) {
    case 4:
      k_stage1<8><<<dim3(512), dim3(256), 0, stream>>>(x, w1, w3, part, wtab);
      k_stage23<4><<<dim3(512), dim3(512), 0, stream>>>(part, w2, b2, b3, b1,
                                                        wtab, out);
      break;
    case 2:
      k_stage1<16><<<dim3(256), dim3(256), 0, stream>>>(x, w1, w3, part, wtab);
      k_stage23<2><<<dim3(512), dim3(512), 0, stream>>>(part, w2, b2, b3, b1,
                                                        wtab, out);
      break;
    default:
      k_stage1<32><<<dim3(128), dim3(256), 0, stream>>>(x, w1, w3, part, wtab);
      k_stage23<1><<<dim3(512), dim3(512), 0, stream>>>(part, w2, b2, b3, b1,
                                                        wtab, out);
      break;
  }
}